// Round 12
// baseline (192.258 us; speedup 1.0000x reference)
//
#include <hip/hip_runtime.h>
#include <hip/hip_bf16.h>

#define BATCH 4096

typedef unsigned short u16;
typedef _Float16 half4 __attribute__((ext_vector_type(4)));
typedef _Float16 half8 __attribute__((ext_vector_type(8)));
typedef short bs8 __attribute__((ext_vector_type(8)));
typedef float floatx4 __attribute__((ext_vector_type(4)));

__device__ inline u16 f2bf(float f) {
    union { float f; unsigned int i; } u;
    u.f = f;
    unsigned int lsb = (u.i >> 16) & 1u;
    unsigned int r = u.i + 0x7fffu + lsb;   // RNE
    if ((u.i & 0x7f800000u) == 0x7f800000u) r = u.i;
    return (u16)(r >> 16);
}

// ---------------------------------------------------------------------------
// Prep: w1h gabor f16 [32][16] (K 9->16 zero-pad); w2h f16 [tap][oc][ic];
//       wbf bf16 [128][3200], k' = oc*50+pl (padded oc-major, pad=0).
// ---------------------------------------------------------------------------
__global__ __launch_bounds__(256) void prep_kernel(
        const float* __restrict__ theta, const float* __restrict__ sigma,
        const float* __restrict__ gamma, const float* __restrict__ lambd,
        const float* __restrict__ psi, const float* __restrict__ conv2_w,
        const float* __restrict__ fc1_w, _Float16* __restrict__ w1h,
        _Float16* __restrict__ w2h, u16* __restrict__ wbf) {
    int id = blockIdx.x * 256 + threadIdx.x;
    if (id < 512) {
        int g = id >> 4, t = id & 15;
        float v = 0.0f;
        if (t < 9) {
            int i = t / 3, j = t % 3;
            float xg = (float)i - 1.0f;      // meshgrid 'ij'
            float yg = (float)j - 1.0f;
            if (g < 16) {
                float th = theta[g];
                float c = cosf(th), s = sinf(th);
                float xt = xg * c + yg * s;
                float yt = -xg * s + yg * c;
                float sx = sigma[g];
                float sy = sx / gamma[g];
                float env = expf(-0.5f *
                                 (xt * xt / (sx * sx) + yt * yt / (sy * sy)));
                float car =
                    cosf(6.28318530717958647692f * xt / lambd[g] + psi[g]);
                v = env * car;
            } else {
                v = (t == 4) ? 1.0f : 0.0f;
            }
        }
        w1h[id] = (_Float16)v;
    } else if (id < 512 + 18432) {
        int t2 = id - 512;
        int tap = t2 / 2048, rem = t2 % 2048;
        int oc = rem / 32, ic = rem % 32;
        w2h[t2] = (_Float16)conv2_w[(oc * 32 + ic) * 9 + tap];
    } else {
        int t3 = id - 512 - 18432;            // < 409600 (grid exact)
        int nrow = t3 / 3200, kp = t3 % 3200;
        int oc = kp / 50, pl = kp % 50;
        wbf[t3] =
            pl < 49 ? f2bf(fc1_w[(size_t)nrow * 3136 + oc * 49 + pl]) : 0;
    }
}

// ---------------------------------------------------------------------------
// Fused conv. conv1 on 16x16x16 MFMA. conv2 on 16x16x32 MFMA with each wave
// covering the FULL N=64 (4 B-frag sets in registers, preloaded before conv1)
// so every A fragment is read from LDS exactly once: 117 ds_read_b128/block.
// a2 layout: (4096)[oc*50+pl] bf16, pads zero.
// ---------------------------------------------------------------------------
__global__ __launch_bounds__(256) void fused_conv_kernel(
        const float* __restrict__ x, const _Float16* __restrict__ w1h,
        const _Float16* __restrict__ w2h, const float* __restrict__ conv2_b,
        u16* __restrict__ a2) {
    __shared__ _Float16 img16[30][32];
    __shared__ __align__(16) _Float16 a1s[16][16][40];
    __shared__ u16 out2[64 * 50];

    int n = blockIdx.x;
    int tid = threadIdx.x;
    int lane = tid & 63;
    int w = tid >> 6;
    int l16 = lane & 15;
    int quad = lane >> 4;

    // ---- conv2 B preload: 9 taps x 4 nt-groups (latency hidden by conv1) --
    // B[oc=nt*16+l16][k=quad*8+i], w2h contiguous in ic.
    half8 bf[9][4];
#pragma unroll
    for (int t = 0; t < 9; ++t)
#pragma unroll
        for (int nt = 0; nt < 4; ++nt)
            bf[t][nt] = *(const half8*)&w2h[(t * 64 + nt * 16 + l16) * 32 +
                                            quad * 8];
    float bias[4];
#pragma unroll
    for (int nt = 0; nt < 4; ++nt) bias[nt] = conv2_b[nt * 16 + l16];

    for (int i = tid; i < 120; i += 256) ((int4*)&img16[0][0])[i] = int4{0,0,0,0};
    for (int i = tid; i < 1280; i += 256) ((int4*)&a1s[0][0][0])[i] = int4{0,0,0,0};
    for (int i = tid; i < 400; i += 256) ((int4*)&out2[0])[i] = int4{0,0,0,0};
    __syncthreads();

    const float* xim = x + (size_t)n * 784;
    for (int i = tid; i < 784; i += 256)
        img16[i / 28 + 1][i % 28 + 1] = (_Float16)xim[i];
    __syncthreads();

    // ---- conv1 MFMA: M pool-major, N=32, K=16 (9 taps; B zero-padded so
    //      A lanes with t>=9 may read garbage -> clamp offsets to tap 8) ----
    half4 b1a = *(const half4*)&w1h[l16 * 16 + quad * 4];
    half4 b1b = *(const half4*)&w1h[(16 + l16) * 16 + quad * 4];
    int t0 = quad * 4;
    int u0 = t0 < 9 ? t0 : 8, u1 = t0 + 1 < 9 ? t0 + 1 : 8;
    int u2 = t0 + 2 < 9 ? t0 + 2 : 8, u3 = t0 + 3 < 9 ? t0 + 3 : 8;
    int off0 = (u0 / 3) * 32 + (u0 % 3);
    int off1 = (u1 / 3) * 32 + (u1 % 3);
    int off2 = (u2 / 3) * 32 + (u2 % 3);
    int off3 = (u3 / 3) * 32 + (u3 % 3);
    int sy = (l16 & 3) >> 1, sx = l16 & 1;

    int pool0 = w * 4 + (l16 >> 2);
    int a14 = pool0 >= 14 ? 1 : 0;
    int b14 = pool0 - 14 * a14;
    int pl0 = w * 4 + quad;
    int pa = pl0 >= 14 ? 1 : 0;
    int pb = pl0 - 14 * pa;

    for (int mt = w; mt < 49; mt += 4) {
        const _Float16* p = &img16[2 * a14 + sy][2 * b14 + sx];
        half4 av;
        av[0] = p[off0];
        av[1] = p[off1];
        av[2] = p[off2];
        av[3] = p[off3];
        floatx4 c0 = {0.f, 0.f, 0.f, 0.f};
        floatx4 c1 = {0.f, 0.f, 0.f, 0.f};
        c0 = __builtin_amdgcn_mfma_f32_16x16x16f16(av, b1a, c0, 0, 0, 0);
        c1 = __builtin_amdgcn_mfma_f32_16x16x16f16(av, b1b, c1, 0, 0, 0);
        float m0 = fmaxf(fmaxf(c0[0], c0[1]), fmaxf(c0[2], c0[3]));
        float m1 = fmaxf(fmaxf(c1[0], c1[1]), fmaxf(c1[2], c1[3]));
        a1s[1 + pa][1 + pb][l16] = (_Float16)fmaxf(m0, 0.0f);
        a1s[1 + pa][1 + pb][16 + l16] = (_Float16)fmaxf(m1, 0.0f);
        a14 += 1; b14 += 2;
        if (b14 >= 14) { b14 -= 14; a14 += 1; }
        pa += 1; pb += 2;
        if (pb >= 14) { pb -= 14; pa += 1; }
    }
    __syncthreads();

    // ---- conv2 MFMA 16x16x32: 13 M-tiles over 4 waves, N=64 per wave ----
    u16* o2 = &out2[l16 * 50];
    for (int mt = w; mt < 13; mt += 4) {
        int m = mt * 16 + l16;           // pool-major: pool=m>>2, sub=m&3
        int pool = m >> 2;
        int sub = m & 3;
        int pc = pool < 49 ? pool : 48;
        int y = 2 * (pc / 7) + (sub >> 1);
        int xq = 2 * (pc % 7) + (sub & 1);
        const _Float16* ap = &a1s[y][xq][quad * 8];
        floatx4 a0 = {0.f, 0.f, 0.f, 0.f};
        floatx4 a1 = {0.f, 0.f, 0.f, 0.f};
        floatx4 a2c = {0.f, 0.f, 0.f, 0.f};
        floatx4 a3 = {0.f, 0.f, 0.f, 0.f};
#pragma unroll
        for (int t = 0; t < 9; ++t) {
            int ao = ((t / 3) * 16 + (t % 3)) * 40;
            half8 av = *(const half8*)(ap + ao);
            a0 = __builtin_amdgcn_mfma_f32_16x16x32_f16(av, bf[t][0], a0, 0, 0, 0);
            a1 = __builtin_amdgcn_mfma_f32_16x16x32_f16(av, bf[t][1], a1, 0, 0, 0);
            a2c = __builtin_amdgcn_mfma_f32_16x16x32_f16(av, bf[t][2], a2c, 0, 0, 0);
            a3 = __builtin_amdgcn_mfma_f32_16x16x32_f16(av, bf[t][3], a3, 0, 0, 0);
        }
        int pl = mt * 4 + quad;          // lane owns this pool, 4 oc-groups
        if (pl < 49) {
            float m0 = fmaxf(fmaxf(a0[0], a0[1]), fmaxf(a0[2], a0[3]));
            float m1 = fmaxf(fmaxf(a1[0], a1[1]), fmaxf(a1[2], a1[3]));
            float m2 = fmaxf(fmaxf(a2c[0], a2c[1]), fmaxf(a2c[2], a2c[3]));
            float m3 = fmaxf(fmaxf(a3[0], a3[1]), fmaxf(a3[2], a3[3]));
            o2[pl] = f2bf(fmaxf(m0 + bias[0], 0.0f));
            o2[16 * 50 + pl] = f2bf(fmaxf(m1 + bias[1], 0.0f));
            o2[32 * 50 + pl] = f2bf(fmaxf(m2 + bias[2], 0.0f));
            o2[48 * 50 + pl] = f2bf(fmaxf(m3 + bias[3], 0.0f));
        }
    }
    __syncthreads();

    // ---- contiguous copy LDS -> a2 ----
    uint2* dst = (uint2*)(a2 + (size_t)n * 3200);
    const uint2* src = (const uint2*)out2;
    for (int i = tid; i < 800; i += 256) dst[i] = src[i];
}

// ---------------------------------------------------------------------------
// fc1 + fc2, 256 blocks x 1024 thr (16 waves = 8 strided K-eighths x 2
// N-halves, 4 acc chains) -> 4 waves/SIMD. Hs[8] tree reduce, fc2 in-block.
// ---------------------------------------------------------------------------
__global__ __launch_bounds__(1024) void fc_kernel(
        const u16* __restrict__ A, const u16* __restrict__ Wbf,
        const float* __restrict__ fc1_b, const float* __restrict__ fc2_w,
        const float* __restrict__ fc2_b, float* __restrict__ out) {
    __shared__ float Hs[8][16][132];
    int tid = threadIdx.x;
    int lane = tid & 63;
    int w = tid >> 6;                  // 0..15
    int l16 = lane & 15;
    int quad = lane >> 4;
    int kq = w >> 1;                   // 0..7, strided K-eighth
    int nh = w & 1;                    // N-half
    int m0 = blockIdx.x * 16;

    const u16* aptr = A + (size_t)(m0 + l16) * 3200 + quad * 8;
    const u16* b0 = Wbf + (size_t)(nh * 64 + l16) * 3200 + quad * 8;
    const u16* b1 = b0 + 16 * 3200;
    const u16* b2 = b0 + 32 * 3200;
    const u16* b3 = b0 + 48 * 3200;

    floatx4 ac0 = {0.f, 0.f, 0.f, 0.f};
    floatx4 ac1 = {0.f, 0.f, 0.f, 0.f};
    floatx4 ac2 = {0.f, 0.f, 0.f, 0.f};
    floatx4 ac3 = {0.f, 0.f, 0.f, 0.f};
#pragma unroll 4
    for (int s = kq; s < 100; s += 8) {
        int k0 = s * 32;
        bs8 av = *(const bs8*)(aptr + k0);
        bs8 bv0 = *(const bs8*)(b0 + k0);
        bs8 bv1 = *(const bs8*)(b1 + k0);
        bs8 bv2 = *(const bs8*)(b2 + k0);
        bs8 bv3 = *(const bs8*)(b3 + k0);
        ac0 = __builtin_amdgcn_mfma_f32_16x16x32_bf16(av, bv0, ac0, 0, 0, 0);
        ac1 = __builtin_amdgcn_mfma_f32_16x16x32_bf16(av, bv1, ac1, 0, 0, 0);
        ac2 = __builtin_amdgcn_mfma_f32_16x16x32_bf16(av, bv2, ac2, 0, 0, 0);
        ac3 = __builtin_amdgcn_mfma_f32_16x16x32_bf16(av, bv3, ac3, 0, 0, 0);
    }
    int nb = nh * 64 + l16;
#pragma unroll
    for (int r = 0; r < 4; ++r) {
        int mr = quad * 4 + r;
        Hs[kq][mr][nb] = ac0[r];
        Hs[kq][mr][nb + 16] = ac1[r];
        Hs[kq][mr][nb + 32] = ac2[r];
        Hs[kq][mr][nb + 48] = ac3[r];
    }
    __syncthreads();

    for (int i = tid; i < 2048; i += 1024) {
        int m = i >> 7, k = i & 127;
        float s = Hs[0][m][k] + Hs[1][m][k] + Hs[2][m][k] + Hs[3][m][k] +
                  Hs[4][m][k] + Hs[5][m][k] + Hs[6][m][k] + Hs[7][m][k];
        Hs[0][m][k] = s;
    }
    __syncthreads();

    if (tid < 160) {
        int m = tid / 10, j = tid % 10;
        const float* wr = fc2_w + j * 128;
        float acc = fc2_b[j];
#pragma unroll 16
        for (int k = 0; k < 128; ++k)
            acc += fmaxf(Hs[0][m][k] + fc1_b[k], 0.0f) * wr[k];
        out[(size_t)(m0 + m) * 10 + j] = acc;
    }
}

extern "C" void kernel_launch(void* const* d_in, const int* in_sizes, int n_in,
                              void* d_out, int out_size, void* d_ws,
                              size_t ws_size, hipStream_t stream) {
    const float* x       = (const float*)d_in[0];
    const float* theta   = (const float*)d_in[1];
    const float* sigma   = (const float*)d_in[2];
    const float* gamma   = (const float*)d_in[3];
    const float* lambd   = (const float*)d_in[4];
    const float* psi     = (const float*)d_in[5];
    const float* conv2_w = (const float*)d_in[6];
    const float* conv2_b = (const float*)d_in[7];
    const float* fc1_w   = (const float*)d_in[8];
    const float* fc1_b   = (const float*)d_in[9];
    const float* fc2_w   = (const float*)d_in[10];
    const float* fc2_b   = (const float*)d_in[11];
    float* out = (float*)d_out;

    // ws (27.07 MB):
    //   a2  bf16 [4096][3200]  : 0          (26,214,400 B)
    //   w1h f16 [32][16]       : 26,214,400 (1,024 B)
    //   w2h f16 [9][64][32]    : 26,215,424 (36,864 B)
    //   wbf bf16 [128][3200]   : 26,252,288 (819,200 B)
    char* ws = (char*)d_ws;
    u16* a2 = (u16*)ws;
    _Float16* w1h = (_Float16*)(ws + 26214400ull);
    _Float16* w2h = (_Float16*)(ws + 26215424ull);
    u16* wbf = (u16*)(ws + 26252288ull);

    prep_kernel<<<1674, 256, 0, stream>>>(theta, sigma, gamma, lambd, psi,
                                          conv2_w, fc1_w, w1h, w2h, wbf);
    fused_conv_kernel<<<BATCH, 256, 0, stream>>>(x, w1h, w2h, conv2_b, a2);
    fc_kernel<<<BATCH / 16, 1024, 0, stream>>>(a2, wbf, fc1_b, fc2_w, fc2_b,
                                               out);
}

// Round 13
// 165.577 us; speedup vs baseline: 1.1611x; 1.1611x over previous
//
#include <hip/hip_runtime.h>
#include <hip/hip_bf16.h>

#define BATCH 4096

typedef unsigned short u16;
typedef _Float16 half2v __attribute__((ext_vector_type(2)));
typedef _Float16 half4 __attribute__((ext_vector_type(4)));
typedef _Float16 half8 __attribute__((ext_vector_type(8)));
typedef short bs8 __attribute__((ext_vector_type(8)));
typedef float floatx4 __attribute__((ext_vector_type(4)));
typedef float floatx16 __attribute__((ext_vector_type(16)));

__device__ inline u16 f2bf(float f) {           // prep-only (cold path)
    union { float f; unsigned int i; } u;
    u.f = f;
    unsigned int lsb = (u.i >> 16) & 1u;
    unsigned int r = u.i + 0x7fffu + lsb;       // RNE
    if ((u.i & 0x7f800000u) == 0x7f800000u) r = u.i;
    return (u16)(r >> 16);
}
__device__ inline u16 f2bf_hw(float f) {        // hot path: HW cvt
    __hip_bfloat16 b = __float2bfloat16(f);
    return *(u16*)&b;
}

// ---------------------------------------------------------------------------
// Prep: w1h gabor f16 [32][16] (K 9->16 zero-pad); w2h f16 [tap][oc][k] with
//       ic INTERLEAVED (k=2c+p <-> channel c+16p) to match conv1's packed
//       b32 stores; wbf bf16 [128][3200], k' = oc*50+pl (pad=0).
// ---------------------------------------------------------------------------
__global__ __launch_bounds__(256) void prep_kernel(
        const float* __restrict__ theta, const float* __restrict__ sigma,
        const float* __restrict__ gamma, const float* __restrict__ lambd,
        const float* __restrict__ psi, const float* __restrict__ conv2_w,
        const float* __restrict__ fc1_w, _Float16* __restrict__ w1h,
        _Float16* __restrict__ w2h, u16* __restrict__ wbf) {
    int id = blockIdx.x * 256 + threadIdx.x;
    if (id < 512) {
        int g = id >> 4, t = id & 15;
        float v = 0.0f;
        if (t < 9) {
            int i = t / 3, j = t % 3;
            float xg = (float)i - 1.0f;      // meshgrid 'ij'
            float yg = (float)j - 1.0f;
            if (g < 16) {
                float th = theta[g];
                float c = cosf(th), s = sinf(th);
                float xt = xg * c + yg * s;
                float yt = -xg * s + yg * c;
                float sx = sigma[g];
                float sy = sx / gamma[g];
                float env = expf(-0.5f *
                                 (xt * xt / (sx * sx) + yt * yt / (sy * sy)));
                float car =
                    cosf(6.28318530717958647692f * xt / lambd[g] + psi[g]);
                v = env * car;
            } else {
                v = (t == 4) ? 1.0f : 0.0f;
            }
        }
        w1h[id] = (_Float16)v;
    } else if (id < 512 + 18432) {
        int t2 = id - 512;
        int tap = t2 / 2048, rem = t2 % 2048;
        int oc = rem / 32, k = rem % 32;
        int ic = (k >> 1) + 16 * (k & 1);     // interleaved channel order
        w2h[t2] = (_Float16)conv2_w[(oc * 32 + ic) * 9 + tap];
    } else {
        int t3 = id - 512 - 18432;            // < 409600 (grid exact)
        int nrow = t3 / 3200, kp = t3 % 3200;
        int oc = kp / 50, pl = kp % 50;
        wbf[t3] =
            pl < 49 ? f2bf(fc1_w[(size_t)nrow * 3136 + oc * 49 + pl]) : 0;
    }
}

// ---------------------------------------------------------------------------
// Fused conv (r11 structure). conv1 on 16x16x16 MFMA with clamped tap offsets
// (w1h rows k>=9 are zero) and packed half2 ds_write_b32 stores. conv2 on
// 32x32x16 MFMA, nt fixed per wave, B preloaded to regs before conv1.
// a2 layout: (4096)[oc*50+pl] bf16, pads zero.
// ---------------------------------------------------------------------------
__global__ __launch_bounds__(256) void fused_conv_kernel(
        const float* __restrict__ x, const _Float16* __restrict__ w1h,
        const _Float16* __restrict__ w2h, const float* __restrict__ conv2_b,
        u16* __restrict__ a2) {
    __shared__ _Float16 img16[30][32];
    __shared__ __align__(16) _Float16 a1s[16][16][40];
    __shared__ u16 out2[64 * 50];

    int n = blockIdx.x;
    int tid = threadIdx.x;
    int lane = tid & 63;
    int w = tid >> 6;
    int l16 = lane & 15;
    int quad = lane >> 4;
    int l32 = lane & 31;
    int h = lane >> 5;

    // ---- conv2 B-fragment preload (global/L2), latency hidden by conv1 ----
    int nt = w & 1;
    int mt0 = w >> 1;
    int oc = nt * 32 + l32;
    half8 bE[9], bO[9];
    const _Float16* bp = w2h + (size_t)oc * 32 + h * 8;
#pragma unroll
    for (int t = 0; t < 9; ++t) {
        bE[t] = *(const half8*)(bp + t * 2048);
        bO[t] = *(const half8*)(bp + t * 2048 + 16);
    }
    float bias = conv2_b[oc];

    for (int i = tid; i < 120; i += 256) ((int4*)&img16[0][0])[i] = int4{0,0,0,0};
    for (int i = tid; i < 1280; i += 256) ((int4*)&a1s[0][0][0])[i] = int4{0,0,0,0};
    for (int i = tid; i < 400; i += 256) ((int4*)&out2[0])[i] = int4{0,0,0,0};
    __syncthreads();

    const float* xim = x + (size_t)n * 784;
    for (int i = tid; i < 784; i += 256)
        img16[i / 28 + 1][i % 28 + 1] = (_Float16)xim[i];
    __syncthreads();

    // ---- conv1 MFMA: M pool-major, N=32, K=16 (taps >=9 clamped; B rows
    //      zero there so garbage A values contribute nothing) ----
    half4 b1a = *(const half4*)&w1h[l16 * 16 + quad * 4];
    half4 b1b = *(const half4*)&w1h[(16 + l16) * 16 + quad * 4];
    int t0 = quad * 4;
    int u0 = t0 < 9 ? t0 : 8, u1 = t0 + 1 < 9 ? t0 + 1 : 8;
    int u2 = t0 + 2 < 9 ? t0 + 2 : 8, u3 = t0 + 3 < 9 ? t0 + 3 : 8;
    int off0 = (u0 / 3) * 32 + (u0 % 3);
    int off1 = (u1 / 3) * 32 + (u1 % 3);
    int off2 = (u2 / 3) * 32 + (u2 % 3);
    int off3 = (u3 / 3) * 32 + (u3 % 3);
    int sy = (l16 & 3) >> 1, sx = l16 & 1;

    int pool0 = w * 4 + (l16 >> 2);
    int a14 = pool0 >= 14 ? 1 : 0;
    int b14 = pool0 - 14 * a14;
    int pl0 = w * 4 + quad;
    int pa = pl0 >= 14 ? 1 : 0;
    int pb = pl0 - 14 * pa;

    for (int mt = w; mt < 49; mt += 4) {
        const _Float16* p = &img16[2 * a14 + sy][2 * b14 + sx];
        half4 av;
        av[0] = p[off0];
        av[1] = p[off1];
        av[2] = p[off2];
        av[3] = p[off3];
        floatx4 c0 = {0.f, 0.f, 0.f, 0.f};
        floatx4 c1 = {0.f, 0.f, 0.f, 0.f};
        c0 = __builtin_amdgcn_mfma_f32_16x16x16f16(av, b1a, c0, 0, 0, 0);
        c1 = __builtin_amdgcn_mfma_f32_16x16x16f16(av, b1b, c1, 0, 0, 0);
        float m0 = fmaxf(fmaxf(c0[0], c0[1]), fmaxf(c0[2], c0[3]));
        float m1 = fmaxf(fmaxf(c1[0], c1[1]), fmaxf(c1[2], c1[3]));
        half2v pk;
        pk[0] = (_Float16)fmaxf(m0, 0.0f);    // channel l16      -> k=2*l16
        pk[1] = (_Float16)fmaxf(m1, 0.0f);    // channel l16+16   -> k=2*l16+1
        *(half2v*)&a1s[1 + pa][1 + pb][2 * l16] = pk;
        a14 += 1; b14 += 2;
        if (b14 >= 14) { b14 -= 14; a14 += 1; }
        pa += 1; pb += 2;
        if (pb >= 14) { pb -= 14; pa += 1; }
    }
    __syncthreads();

    // ---- conv2 MFMA 32x32x16: nt fixed/wave, mts strided by 2 ----
    for (int mt = mt0; mt < 7; mt += 2) {
        int pool = mt * 8 + (l32 >> 2);
        int sub = l32 & 3;
        int pc = pool < 49 ? pool : 48;
        int y = 2 * (pc / 7) + (sub >> 1);
        int xq = 2 * (pc % 7) + (sub & 1);
        const _Float16* ap = &a1s[y][xq][h * 8];
        floatx16 accE = {};
        floatx16 accO = {};
#pragma unroll
        for (int t = 0; t < 9; ++t) {
            int ao = ((t / 3) * 16 + (t % 3)) * 40;
            half8 avE = *(const half8*)(ap + ao);
            half8 avO = *(const half8*)(ap + ao + 16);
            accE = __builtin_amdgcn_mfma_f32_32x32x16_f16(avE, bE[t], accE,
                                                          0, 0, 0);
            accO = __builtin_amdgcn_mfma_f32_32x32x16_f16(avO, bO[t], accO,
                                                          0, 0, 0);
        }
#pragma unroll
        for (int rg = 0; rg < 4; ++rg) {
            int pl = mt * 8 + 2 * rg + h;
            if (pl < 49) {
                float v0 = accE[rg * 4 + 0] + accO[rg * 4 + 0];
                float v1 = accE[rg * 4 + 1] + accO[rg * 4 + 1];
                float v2 = accE[rg * 4 + 2] + accO[rg * 4 + 2];
                float v3 = accE[rg * 4 + 3] + accO[rg * 4 + 3];
                float mx = fmaxf(fmaxf(v0, v1), fmaxf(v2, v3));
                out2[oc * 50 + pl] = f2bf_hw(fmaxf(mx + bias, 0.0f));
            }
        }
    }
    __syncthreads();

    // ---- contiguous copy LDS -> a2 ----
    uint2* dst = (uint2*)(a2 + (size_t)n * 3200);
    const uint2* src = (const uint2*)out2;
    for (int i = tid; i < 800; i += 256) dst[i] = src[i];
}

// ---------------------------------------------------------------------------
// fc1 + fc2, 256 blocks x 1024 thr (16 waves = 8 strided K-eighths x 2
// N-halves, 4 acc chains) -> 4 waves/SIMD. Hs[8] tree reduce, fc2 in-block.
// ---------------------------------------------------------------------------
__global__ __launch_bounds__(1024) void fc_kernel(
        const u16* __restrict__ A, const u16* __restrict__ Wbf,
        const float* __restrict__ fc1_b, const float* __restrict__ fc2_w,
        const float* __restrict__ fc2_b, float* __restrict__ out) {
    __shared__ float Hs[8][16][132];
    int tid = threadIdx.x;
    int lane = tid & 63;
    int w = tid >> 6;                  // 0..15
    int l16 = lane & 15;
    int quad = lane >> 4;
    int kq = w >> 1;                   // 0..7, strided K-eighth
    int nh = w & 1;                    // N-half
    int m0 = blockIdx.x * 16;

    const u16* aptr = A + (size_t)(m0 + l16) * 3200 + quad * 8;
    const u16* b0 = Wbf + (size_t)(nh * 64 + l16) * 3200 + quad * 8;
    const u16* b1 = b0 + 16 * 3200;
    const u16* b2 = b0 + 32 * 3200;
    const u16* b3 = b0 + 48 * 3200;

    floatx4 ac0 = {0.f, 0.f, 0.f, 0.f};
    floatx4 ac1 = {0.f, 0.f, 0.f, 0.f};
    floatx4 ac2 = {0.f, 0.f, 0.f, 0.f};
    floatx4 ac3 = {0.f, 0.f, 0.f, 0.f};
#pragma unroll 4
    for (int s = kq; s < 100; s += 8) {
        int k0 = s * 32;
        bs8 av = *(const bs8*)(aptr + k0);
        bs8 bv0 = *(const bs8*)(b0 + k0);
        bs8 bv1 = *(const bs8*)(b1 + k0);
        bs8 bv2 = *(const bs8*)(b2 + k0);
        bs8 bv3 = *(const bs8*)(b3 + k0);
        ac0 = __builtin_amdgcn_mfma_f32_16x16x32_bf16(av, bv0, ac0, 0, 0, 0);
        ac1 = __builtin_amdgcn_mfma_f32_16x16x32_bf16(av, bv1, ac1, 0, 0, 0);
        ac2 = __builtin_amdgcn_mfma_f32_16x16x32_bf16(av, bv2, ac2, 0, 0, 0);
        ac3 = __builtin_amdgcn_mfma_f32_16x16x32_bf16(av, bv3, ac3, 0, 0, 0);
    }
    int nb = nh * 64 + l16;
#pragma unroll
    for (int r = 0; r < 4; ++r) {
        int mr = quad * 4 + r;
        Hs[kq][mr][nb] = ac0[r];
        Hs[kq][mr][nb + 16] = ac1[r];
        Hs[kq][mr][nb + 32] = ac2[r];
        Hs[kq][mr][nb + 48] = ac3[r];
    }
    __syncthreads();

    for (int i = tid; i < 2048; i += 1024) {
        int m = i >> 7, k = i & 127;
        float s = Hs[0][m][k] + Hs[1][m][k] + Hs[2][m][k] + Hs[3][m][k] +
                  Hs[4][m][k] + Hs[5][m][k] + Hs[6][m][k] + Hs[7][m][k];
        Hs[0][m][k] = s;
    }
    __syncthreads();

    if (tid < 160) {
        int m = tid / 10, j = tid % 10;
        const float* wr = fc2_w + j * 128;
        float acc = fc2_b[j];
#pragma unroll 16
        for (int k = 0; k < 128; ++k)
            acc += fmaxf(Hs[0][m][k] + fc1_b[k], 0.0f) * wr[k];
        out[(size_t)(m0 + m) * 10 + j] = acc;
    }
}

extern "C" void kernel_launch(void* const* d_in, const int* in_sizes, int n_in,
                              void* d_out, int out_size, void* d_ws,
                              size_t ws_size, hipStream_t stream) {
    const float* x       = (const float*)d_in[0];
    const float* theta   = (const float*)d_in[1];
    const float* sigma   = (const float*)d_in[2];
    const float* gamma   = (const float*)d_in[3];
    const float* lambd   = (const float*)d_in[4];
    const float* psi     = (const float*)d_in[5];
    const float* conv2_w = (const float*)d_in[6];
    const float* conv2_b = (const float*)d_in[7];
    const float* fc1_w   = (const float*)d_in[8];
    const float* fc1_b   = (const float*)d_in[9];
    const float* fc2_w   = (const float*)d_in[10];
    const float* fc2_b   = (const float*)d_in[11];
    float* out = (float*)d_out;

    // ws (27.07 MB):
    //   a2  bf16 [4096][3200]  : 0          (26,214,400 B)
    //   w1h f16 [32][16]       : 26,214,400 (1,024 B)
    //   w2h f16 [9][64][32]    : 26,215,424 (36,864 B)
    //   wbf bf16 [128][3200]   : 26,252,288 (819,200 B)
    char* ws = (char*)d_ws;
    u16* a2 = (u16*)ws;
    _Float16* w1h = (_Float16*)(ws + 26214400ull);
    _Float16* w2h = (_Float16*)(ws + 26215424ull);
    u16* wbf = (u16*)(ws + 26252288ull);

    prep_kernel<<<1674, 256, 0, stream>>>(theta, sigma, gamma, lambd, psi,
                                          conv2_w, fc1_w, w1h, w2h, wbf);
    fused_conv_kernel<<<BATCH, 256, 0, stream>>>(x, w1h, w2h, conv2_b, a2);
    fc_kernel<<<BATCH / 16, 1024, 0, stream>>>(a2, wbf, fc1_b, fc2_w, fc2_b,
                                               out);
}

// Round 14
// 163.807 us; speedup vs baseline: 1.1737x; 1.0108x over previous
//
#include <hip/hip_runtime.h>
#include <hip/hip_bf16.h>

#define BATCH 4096

typedef unsigned short u16;
typedef _Float16 half2v __attribute__((ext_vector_type(2)));
typedef _Float16 half4 __attribute__((ext_vector_type(4)));
typedef _Float16 half8 __attribute__((ext_vector_type(8)));
typedef short bs8 __attribute__((ext_vector_type(8)));
typedef float floatx4 __attribute__((ext_vector_type(4)));
typedef float floatx16 __attribute__((ext_vector_type(16)));

__device__ inline u16 f2bf(float f) {           // prep-only (cold path)
    union { float f; unsigned int i; } u;
    u.f = f;
    unsigned int lsb = (u.i >> 16) & 1u;
    unsigned int r = u.i + 0x7fffu + lsb;       // RNE
    if ((u.i & 0x7f800000u) == 0x7f800000u) r = u.i;
    return (u16)(r >> 16);
}
__device__ inline u16 f2bf_hw(float f) {        // hot path: HW cvt
    __hip_bfloat16 b = __float2bfloat16(f);
    return *(u16*)&b;
}

// ---------------------------------------------------------------------------
// Prep: w1h gabor f16 [32][16] (K 9->16 zero-pad); w2h f16 [tap][oc][k] with
//       ic INTERLEAVED (k=2c+p <-> channel c+16p) to match conv1's packed
//       b32 stores; wbf bf16 [128][3200], k' = oc*50+pl (pad=0).
// ---------------------------------------------------------------------------
__global__ __launch_bounds__(256) void prep_kernel(
        const float* __restrict__ theta, const float* __restrict__ sigma,
        const float* __restrict__ gamma, const float* __restrict__ lambd,
        const float* __restrict__ psi, const float* __restrict__ conv2_w,
        const float* __restrict__ fc1_w, _Float16* __restrict__ w1h,
        _Float16* __restrict__ w2h, u16* __restrict__ wbf) {
    int id = blockIdx.x * 256 + threadIdx.x;
    if (id < 512) {
        int g = id >> 4, t = id & 15;
        float v = 0.0f;
        if (t < 9) {
            int i = t / 3, j = t % 3;
            float xg = (float)i - 1.0f;      // meshgrid 'ij'
            float yg = (float)j - 1.0f;
            if (g < 16) {
                float th = theta[g];
                float c = cosf(th), s = sinf(th);
                float xt = xg * c + yg * s;
                float yt = -xg * s + yg * c;
                float sx = sigma[g];
                float sy = sx / gamma[g];
                float env = expf(-0.5f *
                                 (xt * xt / (sx * sx) + yt * yt / (sy * sy)));
                float car =
                    cosf(6.28318530717958647692f * xt / lambd[g] + psi[g]);
                v = env * car;
            } else {
                v = (t == 4) ? 1.0f : 0.0f;
            }
        }
        w1h[id] = (_Float16)v;
    } else if (id < 512 + 18432) {
        int t2 = id - 512;
        int tap = t2 / 2048, rem = t2 % 2048;
        int oc = rem / 32, k = rem % 32;
        int ic = (k >> 1) + 16 * (k & 1);     // interleaved channel order
        w2h[t2] = (_Float16)conv2_w[(oc * 32 + ic) * 9 + tap];
    } else {
        int t3 = id - 512 - 18432;            // < 409600 (grid exact)
        int nrow = t3 / 3200, kp = t3 % 3200;
        int oc = kp / 50, pl = kp % 50;
        wbf[t3] =
            pl < 49 ? f2bf(fc1_w[(size_t)nrow * 3136 + oc * 49 + pl]) : 0;
    }
}

// ---------------------------------------------------------------------------
// Fused conv, TWO images per 512-thread block (waves 0-3 -> image 0,
// waves 4-7 -> image 1; identical phase lengths so shared barriers are free).
// Per-image structure = round-13: conv1 16x16x16 MFMA, conv2 32x32x16 MFMA
// with nt fixed per wave and B preloaded to registers before conv1.
// LDS 57.6 KB/block -> 2 blocks/CU -> 16 waves/CU (vs 8.6 measured at r13).
// a2 layout: (4096)[oc*50+pl] bf16, pads zero.
// ---------------------------------------------------------------------------
__global__ __launch_bounds__(512) void fused_conv_kernel(
        const float* __restrict__ x, const _Float16* __restrict__ w1h,
        const _Float16* __restrict__ w2h, const float* __restrict__ conv2_b,
        u16* __restrict__ a2) {
    __shared__ _Float16 img16[2][30][32];
    __shared__ __align__(16) _Float16 a1s[2][16][16][40];
    __shared__ u16 out2[2][64 * 50];

    int tid = threadIdx.x;
    int im = tid >> 8;                 // image slot 0/1
    int t = tid & 255;                 // within-image thread id
    int n = blockIdx.x * 2 + im;
    int lane = t & 63;
    int w = t >> 6;                    // wave-within-image 0..3
    int l16 = lane & 15;
    int quad = lane >> 4;
    int l32 = lane & 31;
    int h = lane >> 5;

    // ---- conv2 B-fragment preload (global/L2), latency hidden by conv1 ----
    int nt = w & 1;
    int mt0 = w >> 1;
    int oc = nt * 32 + l32;
    half8 bE[9], bO[9];
    const _Float16* bp = w2h + (size_t)oc * 32 + h * 8;
#pragma unroll
    for (int tt = 0; tt < 9; ++tt) {
        bE[tt] = *(const half8*)(bp + tt * 2048);
        bO[tt] = *(const half8*)(bp + tt * 2048 + 16);
    }
    float bias = conv2_b[oc];

    for (int i = t; i < 120; i += 256)
        ((int4*)&img16[im][0][0])[i] = int4{0, 0, 0, 0};
    for (int i = t; i < 1280; i += 256)
        ((int4*)&a1s[im][0][0][0])[i] = int4{0, 0, 0, 0};
    for (int i = t; i < 400; i += 256)
        ((int4*)&out2[im][0])[i] = int4{0, 0, 0, 0};
    __syncthreads();

    const float* xim = x + (size_t)n * 784;
    for (int i = t; i < 784; i += 256)
        img16[im][i / 28 + 1][i % 28 + 1] = (_Float16)xim[i];
    __syncthreads();

    // ---- conv1 MFMA: M pool-major, N=32, K=16 (taps >=9 clamped; B rows
    //      zero there so garbage A values contribute nothing) ----
    half4 b1a = *(const half4*)&w1h[l16 * 16 + quad * 4];
    half4 b1b = *(const half4*)&w1h[(16 + l16) * 16 + quad * 4];
    int t0 = quad * 4;
    int u0 = t0 < 9 ? t0 : 8, u1 = t0 + 1 < 9 ? t0 + 1 : 8;
    int u2 = t0 + 2 < 9 ? t0 + 2 : 8, u3 = t0 + 3 < 9 ? t0 + 3 : 8;
    int off0 = (u0 / 3) * 32 + (u0 % 3);
    int off1 = (u1 / 3) * 32 + (u1 % 3);
    int off2 = (u2 / 3) * 32 + (u2 % 3);
    int off3 = (u3 / 3) * 32 + (u3 % 3);
    int sy = (l16 & 3) >> 1, sx = l16 & 1;

    int pool0 = w * 4 + (l16 >> 2);
    int a14 = pool0 >= 14 ? 1 : 0;
    int b14 = pool0 - 14 * a14;
    int pl0 = w * 4 + quad;
    int pa = pl0 >= 14 ? 1 : 0;
    int pb = pl0 - 14 * pa;

    for (int mt = w; mt < 49; mt += 4) {
        const _Float16* p = &img16[im][2 * a14 + sy][2 * b14 + sx];
        half4 av;
        av[0] = p[off0];
        av[1] = p[off1];
        av[2] = p[off2];
        av[3] = p[off3];
        floatx4 c0 = {0.f, 0.f, 0.f, 0.f};
        floatx4 c1 = {0.f, 0.f, 0.f, 0.f};
        c0 = __builtin_amdgcn_mfma_f32_16x16x16f16(av, b1a, c0, 0, 0, 0);
        c1 = __builtin_amdgcn_mfma_f32_16x16x16f16(av, b1b, c1, 0, 0, 0);
        float m0 = fmaxf(fmaxf(c0[0], c0[1]), fmaxf(c0[2], c0[3]));
        float m1 = fmaxf(fmaxf(c1[0], c1[1]), fmaxf(c1[2], c1[3]));
        half2v pk;
        pk[0] = (_Float16)fmaxf(m0, 0.0f);    // channel l16    -> k=2*l16
        pk[1] = (_Float16)fmaxf(m1, 0.0f);    // channel l16+16 -> k=2*l16+1
        *(half2v*)&a1s[im][1 + pa][1 + pb][2 * l16] = pk;
        a14 += 1; b14 += 2;
        if (b14 >= 14) { b14 -= 14; a14 += 1; }
        pa += 1; pb += 2;
        if (pb >= 14) { pb -= 14; pa += 1; }
    }
    __syncthreads();

    // ---- conv2 MFMA 32x32x16: nt fixed/wave, mts strided by 2 ----
    for (int mt = mt0; mt < 7; mt += 2) {
        int pool = mt * 8 + (l32 >> 2);
        int sub = l32 & 3;
        int pc = pool < 49 ? pool : 48;
        int y = 2 * (pc / 7) + (sub >> 1);
        int xq = 2 * (pc % 7) + (sub & 1);
        const _Float16* ap = &a1s[im][y][xq][h * 8];
        floatx16 accE = {};
        floatx16 accO = {};
#pragma unroll
        for (int tt = 0; tt < 9; ++tt) {
            int ao = ((tt / 3) * 16 + (tt % 3)) * 40;
            half8 avE = *(const half8*)(ap + ao);
            half8 avO = *(const half8*)(ap + ao + 16);
            accE = __builtin_amdgcn_mfma_f32_32x32x16_f16(avE, bE[tt], accE,
                                                          0, 0, 0);
            accO = __builtin_amdgcn_mfma_f32_32x32x16_f16(avO, bO[tt], accO,
                                                          0, 0, 0);
        }
#pragma unroll
        for (int rg = 0; rg < 4; ++rg) {
            int pl = mt * 8 + 2 * rg + h;
            if (pl < 49) {
                float v0 = accE[rg * 4 + 0] + accO[rg * 4 + 0];
                float v1 = accE[rg * 4 + 1] + accO[rg * 4 + 1];
                float v2 = accE[rg * 4 + 2] + accO[rg * 4 + 2];
                float v3 = accE[rg * 4 + 3] + accO[rg * 4 + 3];
                float mx = fmaxf(fmaxf(v0, v1), fmaxf(v2, v3));
                out2[im][oc * 50 + pl] = f2bf_hw(fmaxf(mx + bias, 0.0f));
            }
        }
    }
    __syncthreads();

    // ---- contiguous copy LDS -> a2 ----
    uint2* dst = (uint2*)(a2 + (size_t)n * 3200);
    const uint2* src = (const uint2*)&out2[im][0];
    for (int i = t; i < 800; i += 256) dst[i] = src[i];
}

// ---------------------------------------------------------------------------
// fc1 + fc2, 256 blocks x 1024 thr (16 waves = 8 strided K-eighths x 2
// N-halves, 4 acc chains) -> 4 waves/SIMD. Hs[8] tree reduce, fc2 in-block.
// ---------------------------------------------------------------------------
__global__ __launch_bounds__(1024) void fc_kernel(
        const u16* __restrict__ A, const u16* __restrict__ Wbf,
        const float* __restrict__ fc1_b, const float* __restrict__ fc2_w,
        const float* __restrict__ fc2_b, float* __restrict__ out) {
    __shared__ float Hs[8][16][132];
    int tid = threadIdx.x;
    int lane = tid & 63;
    int w = tid >> 6;                  // 0..15
    int l16 = lane & 15;
    int quad = lane >> 4;
    int kq = w >> 1;                   // 0..7, strided K-eighth
    int nh = w & 1;                    // N-half
    int m0 = blockIdx.x * 16;

    const u16* aptr = A + (size_t)(m0 + l16) * 3200 + quad * 8;
    const u16* b0 = Wbf + (size_t)(nh * 64 + l16) * 3200 + quad * 8;
    const u16* b1 = b0 + 16 * 3200;
    const u16* b2 = b0 + 32 * 3200;
    const u16* b3 = b0 + 48 * 3200;

    floatx4 ac0 = {0.f, 0.f, 0.f, 0.f};
    floatx4 ac1 = {0.f, 0.f, 0.f, 0.f};
    floatx4 ac2 = {0.f, 0.f, 0.f, 0.f};
    floatx4 ac3 = {0.f, 0.f, 0.f, 0.f};
#pragma unroll 4
    for (int s = kq; s < 100; s += 8) {
        int k0 = s * 32;
        bs8 av = *(const bs8*)(aptr + k0);
        bs8 bv0 = *(const bs8*)(b0 + k0);
        bs8 bv1 = *(const bs8*)(b1 + k0);
        bs8 bv2 = *(const bs8*)(b2 + k0);
        bs8 bv3 = *(const bs8*)(b3 + k0);
        ac0 = __builtin_amdgcn_mfma_f32_16x16x32_bf16(av, bv0, ac0, 0, 0, 0);
        ac1 = __builtin_amdgcn_mfma_f32_16x16x32_bf16(av, bv1, ac1, 0, 0, 0);
        ac2 = __builtin_amdgcn_mfma_f32_16x16x32_bf16(av, bv2, ac2, 0, 0, 0);
        ac3 = __builtin_amdgcn_mfma_f32_16x16x32_bf16(av, bv3, ac3, 0, 0, 0);
    }
    int nb = nh * 64 + l16;
#pragma unroll
    for (int r = 0; r < 4; ++r) {
        int mr = quad * 4 + r;
        Hs[kq][mr][nb] = ac0[r];
        Hs[kq][mr][nb + 16] = ac1[r];
        Hs[kq][mr][nb + 32] = ac2[r];
        Hs[kq][mr][nb + 48] = ac3[r];
    }
    __syncthreads();

    for (int i = tid; i < 2048; i += 1024) {
        int m = i >> 7, k = i & 127;
        float s = Hs[0][m][k] + Hs[1][m][k] + Hs[2][m][k] + Hs[3][m][k] +
                  Hs[4][m][k] + Hs[5][m][k] + Hs[6][m][k] + Hs[7][m][k];
        Hs[0][m][k] = s;
    }
    __syncthreads();

    if (tid < 160) {
        int m = tid / 10, j = tid % 10;
        const float* wr = fc2_w + j * 128;
        float acc = fc2_b[j];
#pragma unroll 16
        for (int k = 0; k < 128; ++k)
            acc += fmaxf(Hs[0][m][k] + fc1_b[k], 0.0f) * wr[k];
        out[(size_t)(m0 + m) * 10 + j] = acc;
    }
}

extern "C" void kernel_launch(void* const* d_in, const int* in_sizes, int n_in,
                              void* d_out, int out_size, void* d_ws,
                              size_t ws_size, hipStream_t stream) {
    const float* x       = (const float*)d_in[0];
    const float* theta   = (const float*)d_in[1];
    const float* sigma   = (const float*)d_in[2];
    const float* gamma   = (const float*)d_in[3];
    const float* lambd   = (const float*)d_in[4];
    const float* psi     = (const float*)d_in[5];
    const float* conv2_w = (const float*)d_in[6];
    const float* conv2_b = (const float*)d_in[7];
    const float* fc1_w   = (const float*)d_in[8];
    const float* fc1_b   = (const float*)d_in[9];
    const float* fc2_w   = (const float*)d_in[10];
    const float* fc2_b   = (const float*)d_in[11];
    float* out = (float*)d_out;

    // ws (27.07 MB):
    //   a2  bf16 [4096][3200]  : 0          (26,214,400 B)
    //   w1h f16 [32][16]       : 26,214,400 (1,024 B)
    //   w2h f16 [9][64][32]    : 26,215,424 (36,864 B)
    //   wbf bf16 [128][3200]   : 26,252,288 (819,200 B)
    char* ws = (char*)d_ws;
    u16* a2 = (u16*)ws;
    _Float16* w1h = (_Float16*)(ws + 26214400ull);
    _Float16* w2h = (_Float16*)(ws + 26215424ull);
    u16* wbf = (u16*)(ws + 26252288ull);

    prep_kernel<<<1674, 256, 0, stream>>>(theta, sigma, gamma, lambd, psi,
                                          conv2_w, fc1_w, w1h, w2h, wbf);
    fused_conv_kernel<<<BATCH / 2, 512, 0, stream>>>(x, w1h, w2h, conv2_b, a2);
    fc_kernel<<<BATCH / 16, 1024, 0, stream>>>(a2, wbf, fc1_b, fc2_w, fc2_b,
                                               out);
}

// Round 15
// 159.989 us; speedup vs baseline: 1.2017x; 1.0239x over previous
//
#include <hip/hip_runtime.h>
#include <hip/hip_bf16.h>

#define BATCH 4096

typedef unsigned short u16;
typedef _Float16 half2v __attribute__((ext_vector_type(2)));
typedef _Float16 half4 __attribute__((ext_vector_type(4)));
typedef _Float16 half8 __attribute__((ext_vector_type(8)));
typedef short bs8 __attribute__((ext_vector_type(8)));
typedef u16 u16x4 __attribute__((ext_vector_type(4)));
typedef float floatx4 __attribute__((ext_vector_type(4)));
typedef float floatx16 __attribute__((ext_vector_type(16)));

__device__ inline u16 f2bf_hw(float f) {        // HW cvt (RNE)
    __hip_bfloat16 b = __float2bfloat16(f);
    return *(u16*)&b;
}

// ---------------------------------------------------------------------------
// Prep (466 blocks exact): w1h gabor f16 [32][16] (K 9->16 zero-pad);
// w2h f16 [tap][oc][k] ic-interleaved (k=2c+p <-> channel c+16p);
// wbf bf16 [128][3136] = straight vectorized cast of fc1_w (k = oc*49+pl
// natural order — matches a2's oc-major layout with no padding).
// ---------------------------------------------------------------------------
__global__ __launch_bounds__(256) void prep_kernel(
        const float* __restrict__ theta, const float* __restrict__ sigma,
        const float* __restrict__ gamma, const float* __restrict__ lambd,
        const float* __restrict__ psi, const float* __restrict__ conv2_w,
        const float* __restrict__ fc1_w, _Float16* __restrict__ w1h,
        _Float16* __restrict__ w2h, u16* __restrict__ wbf) {
    int id = blockIdx.x * 256 + threadIdx.x;
    if (id < 512) {
        int g = id >> 4, t = id & 15;
        float v = 0.0f;
        if (t < 9) {
            int i = t / 3, j = t % 3;
            float xg = (float)i - 1.0f;      // meshgrid 'ij'
            float yg = (float)j - 1.0f;
            if (g < 16) {
                float th = theta[g];
                float c = cosf(th), s = sinf(th);
                float xt = xg * c + yg * s;
                float yt = -xg * s + yg * c;
                float sx = sigma[g];
                float sy = sx / gamma[g];
                float env = expf(-0.5f *
                                 (xt * xt / (sx * sx) + yt * yt / (sy * sy)));
                float car =
                    cosf(6.28318530717958647692f * xt / lambd[g] + psi[g]);
                v = env * car;
            } else {
                v = (t == 4) ? 1.0f : 0.0f;
            }
        }
        w1h[id] = (_Float16)v;
    } else if (id < 512 + 18432) {
        int t2 = id - 512;
        int tap = t2 / 2048, rem = t2 % 2048;
        int oc = rem / 32, k = rem % 32;
        int ic = (k >> 1) + 16 * (k & 1);     // interleaved channel order
        w2h[t2] = (_Float16)conv2_w[(oc * 32 + ic) * 9 + tap];
    } else {
        int i4 = id - 18944;                  // < 100352 (grid exact)
        float4 v = ((const float4*)fc1_w)[i4];
        u16x4 o;
        o[0] = f2bf_hw(v.x);
        o[1] = f2bf_hw(v.y);
        o[2] = f2bf_hw(v.z);
        o[3] = f2bf_hw(v.w);
        ((u16x4*)wbf)[i4] = o;
    }
}

// ---------------------------------------------------------------------------
// Fused conv, TWO images per 512-thread block (r14 structure).
// conv1 16x16x16 MFMA; conv2 32x32x16 MFMA, nt fixed per wave, B preloaded
// to registers before conv1 (L2 latency hidden under conv1).
// a2 layout: (4096)[oc*49+pl] bf16 (unpadded, every element written).
// ---------------------------------------------------------------------------
__global__ __launch_bounds__(512) void fused_conv_kernel(
        const float* __restrict__ x, const _Float16* __restrict__ w1h,
        const _Float16* __restrict__ w2h, const float* __restrict__ conv2_b,
        u16* __restrict__ a2) {
    __shared__ _Float16 img16[2][30][32];
    __shared__ __align__(16) _Float16 a1s[2][16][16][40];
    __shared__ u16 out2[2][64 * 49];

    int tid = threadIdx.x;
    int im = tid >> 8;                 // image slot 0/1
    int t = tid & 255;                 // within-image thread id
    int n = blockIdx.x * 2 + im;
    int lane = t & 63;
    int w = t >> 6;                    // wave-within-image 0..3
    int l16 = lane & 15;
    int quad = lane >> 4;
    int l32 = lane & 31;
    int h = lane >> 5;

    // ---- conv2 B-fragment preload (global/L2), latency hidden by conv1 ----
    int nt = w & 1;
    int mt0 = w >> 1;
    int oc = nt * 32 + l32;
    half8 bE[9], bO[9];
    const _Float16* bp = w2h + (size_t)oc * 32 + h * 8;
#pragma unroll
    for (int tt = 0; tt < 9; ++tt) {
        bE[tt] = *(const half8*)(bp + tt * 2048);
        bO[tt] = *(const half8*)(bp + tt * 2048 + 16);
    }
    float bias = conv2_b[oc];

    for (int i = t; i < 120; i += 256)
        ((int4*)&img16[im][0][0])[i] = int4{0, 0, 0, 0};
    for (int i = t; i < 1280; i += 256)
        ((int4*)&a1s[im][0][0][0])[i] = int4{0, 0, 0, 0};
    __syncthreads();

    const float* xim = x + (size_t)n * 784;
    for (int i = t; i < 784; i += 256)
        img16[im][i / 28 + 1][i % 28 + 1] = (_Float16)xim[i];
    __syncthreads();

    // ---- conv1 MFMA: M pool-major, N=32, K=16 (taps >=9 clamped; B rows
    //      zero there so garbage A values contribute nothing) ----
    half4 b1a = *(const half4*)&w1h[l16 * 16 + quad * 4];
    half4 b1b = *(const half4*)&w1h[(16 + l16) * 16 + quad * 4];
    int t0 = quad * 4;
    int u0 = t0 < 9 ? t0 : 8, u1 = t0 + 1 < 9 ? t0 + 1 : 8;
    int u2 = t0 + 2 < 9 ? t0 + 2 : 8, u3 = t0 + 3 < 9 ? t0 + 3 : 8;
    int off0 = (u0 / 3) * 32 + (u0 % 3);
    int off1 = (u1 / 3) * 32 + (u1 % 3);
    int off2 = (u2 / 3) * 32 + (u2 % 3);
    int off3 = (u3 / 3) * 32 + (u3 % 3);
    int sy = (l16 & 3) >> 1, sx = l16 & 1;

    int pool0 = w * 4 + (l16 >> 2);
    int a14 = pool0 >= 14 ? 1 : 0;
    int b14 = pool0 - 14 * a14;
    int pl0 = w * 4 + quad;
    int pa = pl0 >= 14 ? 1 : 0;
    int pb = pl0 - 14 * pa;

    for (int mt = w; mt < 49; mt += 4) {
        const _Float16* p = &img16[im][2 * a14 + sy][2 * b14 + sx];
        half4 av;
        av[0] = p[off0];
        av[1] = p[off1];
        av[2] = p[off2];
        av[3] = p[off3];
        floatx4 c0 = {0.f, 0.f, 0.f, 0.f};
        floatx4 c1 = {0.f, 0.f, 0.f, 0.f};
        c0 = __builtin_amdgcn_mfma_f32_16x16x16f16(av, b1a, c0, 0, 0, 0);
        c1 = __builtin_amdgcn_mfma_f32_16x16x16f16(av, b1b, c1, 0, 0, 0);
        float m0 = fmaxf(fmaxf(c0[0], c0[1]), fmaxf(c0[2], c0[3]));
        float m1 = fmaxf(fmaxf(c1[0], c1[1]), fmaxf(c1[2], c1[3]));
        half2v pk;
        pk[0] = (_Float16)fmaxf(m0, 0.0f);    // channel l16    -> k=2*l16
        pk[1] = (_Float16)fmaxf(m1, 0.0f);    // channel l16+16 -> k=2*l16+1
        *(half2v*)&a1s[im][1 + pa][1 + pb][2 * l16] = pk;
        a14 += 1; b14 += 2;
        if (b14 >= 14) { b14 -= 14; a14 += 1; }
        pa += 1; pb += 2;
        if (pb >= 14) { pb -= 14; pa += 1; }
    }
    __syncthreads();

    // ---- conv2 MFMA 32x32x16: nt fixed/wave, mts strided by 2 ----
    for (int mt = mt0; mt < 7; mt += 2) {
        int pool = mt * 8 + (l32 >> 2);
        int sub = l32 & 3;
        int pc = pool < 49 ? pool : 48;
        int y = 2 * (pc / 7) + (sub >> 1);
        int xq = 2 * (pc % 7) + (sub & 1);
        const _Float16* ap = &a1s[im][y][xq][h * 8];
        floatx16 accE = {};
        floatx16 accO = {};
#pragma unroll
        for (int tt = 0; tt < 9; ++tt) {
            int ao = ((tt / 3) * 16 + (tt % 3)) * 40;
            half8 avE = *(const half8*)(ap + ao);
            half8 avO = *(const half8*)(ap + ao + 16);
            accE = __builtin_amdgcn_mfma_f32_32x32x16_f16(avE, bE[tt], accE,
                                                          0, 0, 0);
            accO = __builtin_amdgcn_mfma_f32_32x32x16_f16(avO, bO[tt], accO,
                                                          0, 0, 0);
        }
#pragma unroll
        for (int rg = 0; rg < 4; ++rg) {
            int pl = mt * 8 + 2 * rg + h;
            if (pl < 49) {
                float v0 = accE[rg * 4 + 0] + accO[rg * 4 + 0];
                float v1 = accE[rg * 4 + 1] + accO[rg * 4 + 1];
                float v2 = accE[rg * 4 + 2] + accO[rg * 4 + 2];
                float v3 = accE[rg * 4 + 3] + accO[rg * 4 + 3];
                float mx = fmaxf(fmaxf(v0, v1), fmaxf(v2, v3));
                out2[im][oc * 49 + pl] = f2bf_hw(fmaxf(mx + bias, 0.0f));
            }
        }
    }
    __syncthreads();

    // ---- contiguous copy LDS -> a2 (3136 halfs = 784 uint2) ----
    uint2* dst = (uint2*)(a2 + (size_t)n * 3136);
    const uint2* src = (const uint2*)&out2[im][0];
    for (int i = t; i < 784; i += 256) dst[i] = src[i];
}

// ---------------------------------------------------------------------------
// fc1 + fc2, 256 blocks x 1024 thr (16 waves = 8 strided K-eighths x 2
// N-halves, 4 acc chains) -> 4 waves/SIMD. Hs[8] tree reduce, fc2 in-block.
// K = 3136 = 98 chunks of 32 (kq 0,1 take 13 chunks; others 12).
// ---------------------------------------------------------------------------
__global__ __launch_bounds__(1024) void fc_kernel(
        const u16* __restrict__ A, const u16* __restrict__ Wbf,
        const float* __restrict__ fc1_b, const float* __restrict__ fc2_w,
        const float* __restrict__ fc2_b, float* __restrict__ out) {
    __shared__ float Hs[8][16][132];
    int tid = threadIdx.x;
    int lane = tid & 63;
    int w = tid >> 6;                  // 0..15
    int l16 = lane & 15;
    int quad = lane >> 4;
    int kq = w >> 1;                   // 0..7, strided K-eighth
    int nh = w & 1;                    // N-half
    int m0 = blockIdx.x * 16;

    const u16* aptr = A + (size_t)(m0 + l16) * 3136 + quad * 8;
    const u16* b0 = Wbf + (size_t)(nh * 64 + l16) * 3136 + quad * 8;
    const u16* b1 = b0 + 16 * 3136;
    const u16* b2 = b0 + 32 * 3136;
    const u16* b3 = b0 + 48 * 3136;

    floatx4 ac0 = {0.f, 0.f, 0.f, 0.f};
    floatx4 ac1 = {0.f, 0.f, 0.f, 0.f};
    floatx4 ac2 = {0.f, 0.f, 0.f, 0.f};
    floatx4 ac3 = {0.f, 0.f, 0.f, 0.f};
#pragma unroll 4
    for (int s = kq; s < 98; s += 8) {
        int k0 = s * 32;
        bs8 av = *(const bs8*)(aptr + k0);
        bs8 bv0 = *(const bs8*)(b0 + k0);
        bs8 bv1 = *(const bs8*)(b1 + k0);
        bs8 bv2 = *(const bs8*)(b2 + k0);
        bs8 bv3 = *(const bs8*)(b3 + k0);
        ac0 = __builtin_amdgcn_mfma_f32_16x16x32_bf16(av, bv0, ac0, 0, 0, 0);
        ac1 = __builtin_amdgcn_mfma_f32_16x16x32_bf16(av, bv1, ac1, 0, 0, 0);
        ac2 = __builtin_amdgcn_mfma_f32_16x16x32_bf16(av, bv2, ac2, 0, 0, 0);
        ac3 = __builtin_amdgcn_mfma_f32_16x16x32_bf16(av, bv3, ac3, 0, 0, 0);
    }
    int nb = nh * 64 + l16;
#pragma unroll
    for (int r = 0; r < 4; ++r) {
        int mr = quad * 4 + r;
        Hs[kq][mr][nb] = ac0[r];
        Hs[kq][mr][nb + 16] = ac1[r];
        Hs[kq][mr][nb + 32] = ac2[r];
        Hs[kq][mr][nb + 48] = ac3[r];
    }
    __syncthreads();

    for (int i = tid; i < 2048; i += 1024) {
        int m = i >> 7, k = i & 127;
        float s = Hs[0][m][k] + Hs[1][m][k] + Hs[2][m][k] + Hs[3][m][k] +
                  Hs[4][m][k] + Hs[5][m][k] + Hs[6][m][k] + Hs[7][m][k];
        Hs[0][m][k] = s;
    }
    __syncthreads();

    if (tid < 160) {
        int m = tid / 10, j = tid % 10;
        const float* wr = fc2_w + j * 128;
        float acc = fc2_b[j];
#pragma unroll 16
        for (int k = 0; k < 128; ++k)
            acc += fmaxf(Hs[0][m][k] + fc1_b[k], 0.0f) * wr[k];
        out[(size_t)(m0 + m) * 10 + j] = acc;
    }
}

extern "C" void kernel_launch(void* const* d_in, const int* in_sizes, int n_in,
                              void* d_out, int out_size, void* d_ws,
                              size_t ws_size, hipStream_t stream) {
    const float* x       = (const float*)d_in[0];
    const float* theta   = (const float*)d_in[1];
    const float* sigma   = (const float*)d_in[2];
    const float* gamma   = (const float*)d_in[3];
    const float* lambd   = (const float*)d_in[4];
    const float* psi     = (const float*)d_in[5];
    const float* conv2_w = (const float*)d_in[6];
    const float* conv2_b = (const float*)d_in[7];
    const float* fc1_w   = (const float*)d_in[8];
    const float* fc1_b   = (const float*)d_in[9];
    const float* fc2_w   = (const float*)d_in[10];
    const float* fc2_b   = (const float*)d_in[11];
    float* out = (float*)d_out;

    // ws (26.53 MB, under the 27.07 proven-safe watermark):
    //   a2  bf16 [4096][3136]  : 0          (25,690,112 B)
    //   w1h f16 [32][16]       : 25,690,112 (1,024 B)
    //   w2h f16 [9][64][32]    : 25,691,136 (36,864 B)
    //   wbf bf16 [128][3136]   : 25,728,000 (802,816 B)
    char* ws = (char*)d_ws;
    u16* a2 = (u16*)ws;
    _Float16* w1h = (_Float16*)(ws + 25690112ull);
    _Float16* w2h = (_Float16*)(ws + 25691136ull);
    u16* wbf = (u16*)(ws + 25728000ull);

    prep_kernel<<<466, 256, 0, stream>>>(theta, sigma, gamma, lambd, psi,
                                         conv2_w, fc1_w, w1h, w2h, wbf);
    fused_conv_kernel<<<BATCH / 2, 512, 0, stream>>>(x, w1h, w2h, conv2_b, a2);
    fc_kernel<<<BATCH / 16, 1024, 0, stream>>>(a2, wbf, fc1_b, fc2_w, fc2_b,
                                               out);
}